// Round 1
// baseline (548.440 us; speedup 1.0000x reference)
//
#include <hip/hip_runtime.h>

// LnnDynamics, role-per-block + LDS-weight version:
//   role 0 (m): M-MLP fwd + JVP along qd -> Ms[21] (symmetrized), tc[6]
//   role 1 (u): U-MLP fwd + checkpointed reverse-mode -> tau_pot[6]
//   role 2 (d): D-MLP fwd -> tau_d[6]
//   combine:   r = tau@A - tc - tp - td ; solve Msym y = r
// v2 change: weights+biases are staged into LDS once per 256-thread block
// (one role per block). Previous version read weights via wave-uniform
// s_load streams; per-role working sets (22-34 KB) thrashed the ~16KB
// scalar K$ (3 roles co-resident per CU => ~66KB), and SGPR pressure
// limited prefetch depth => VALUBusy 31%. LDS broadcast reads
// (same-address across lanes = conflict-free) + VGPR prefetch remove the
// scalar-miss stall chain.
// Scratch sc is SoA: sc[field*B + b], fields 0-20 Ms, 21-26 tc, 27-32 tp, 33-38 td.

#define NQ 6
#define HID 32
#define NHID 4  // NL-1

// workspace float offsets (transposed weights, built by prep_kernel)
#define MW0T 0
#define UW0T 192
#define DW0T 384
#define MWHT 576
#define UWHT (576 + 4096)
#define DWHT (576 + 8192)
#define MWOT (576 + 12288)
#define DWOT (MWOT + 1152)
#define UWOT (DWOT + 1152)
#define SC_BASE 16384  // per-element scratch starts here (floats)

// LDS layout (floats):
//  role m/d: [0:192) W0t | [192:4288) Wht | [4288:5440) Wot
//            [5440:5472) b0 | [5472:5600) bh | [5600:5636) bo
//  role u:   [0:192) W0t | [192:4288) Wht | [4288:8384) Wh-original
//            [8384:8416) Wo | [8416:8608) W0-original
//            [8608:8640) b0 | [8640:8768) bh
#define LDS_FLOATS 8768

__global__ void prep_kernel(const float* __restrict__ mW0, const float* __restrict__ mWh,
                            const float* __restrict__ mWo, const float* __restrict__ uW0,
                            const float* __restrict__ uWh, const float* __restrict__ uWo,
                            const float* __restrict__ dW0, const float* __restrict__ dWh,
                            const float* __restrict__ dWo, float* __restrict__ ws) {
  int t = blockIdx.x * blockDim.x + threadIdx.x;
  if (t < 192) {  // W0t[j*6+k] = W0[k*32+j]
    int j = t / 6, k = t % 6;
    ws[MW0T + t] = mW0[k * HID + j];
    ws[UW0T + t] = uW0[k * HID + j];
    ws[DW0T + t] = dW0[k * HID + j];
  }
  if (t < 4096) {  // Wht[(l*32+j)*32+k] = Wh[(l*32+k)*32+j]
    int l = t >> 10, j = (t >> 5) & 31, k = t & 31;
    int src = l * 1024 + k * 32 + j;
    ws[MWHT + t] = mWh[src];
    ws[UWHT + t] = uWh[src];
    ws[DWHT + t] = dWh[src];
  }
  if (t < 1152) {  // Wot[o*32+k] = Wo[k*36+o]
    int o = t / 32, k = t % 32;
    ws[MWOT + t] = mWo[k * 36 + o];
    ws[DWOT + t] = dWo[k * 36 + o];
  }
  if (t < 32) ws[UWOT + t] = uWo[t];
}

__device__ __forceinline__ float sp1(float z) {
  return fmaxf(z, 0.f) + __logf(1.f + __expf(-fabsf(z)));
}
__device__ __forceinline__ void sp_sig(float z, float& hs, float& sg) {
  float e = __expf(-fabsf(z));
  float d = __builtin_amdgcn_rcpf(1.f + e);
  hs = fmaxf(z, 0.f) + __logf(1.f + e);
  sg = (z >= 0.f ? 1.f : e) * d;
}
// h = softplus(z) >= 0  =>  sigmoid(z) = 1 - exp(-h)
__device__ __forceinline__ float sig_h(float h) { return 1.f - __expf(-h); }

// block-cooperative copies into LDS (256 threads)
__device__ __forceinline__ void cpy4(float* __restrict__ dst, const float* __restrict__ src,
                                     int n4, int t) {
  const float4* s = (const float4*)src;
  float4* d = (float4*)dst;
  for (int i = t; i < n4; i += 256) d[i] = s[i];
}
__device__ __forceinline__ void cpys(float* __restrict__ dst, const float* __restrict__ src, int n,
                                     int t) {
  for (int i = t; i < n; i += 256) dst[i] = src[i];
}

// m-role layer, two-pass (keeps only h + tin + tout live):
//   pass A: tout_j = zh_j = h . Wt_j + b_j
//   pass B: zt_j = tin . Wt_j ; h_j = softplus(zh_j) ; tout_j = zt_j * sigmoid(zh_j)
__device__ __forceinline__ void m_layer(const float* __restrict__ Wb, const float* __restrict__ bh,
                                        float* __restrict__ h, const float* __restrict__ tin,
                                        float* __restrict__ tout) {
#pragma unroll
  for (int j = 0; j < 32; j++) {
    const float* r = Wb + j * 32;
    float z = bh[j];
#pragma unroll
    for (int k = 0; k < 32; k++) z += h[k] * r[k];
    tout[j] = z;
  }
#pragma unroll
  for (int j = 0; j < 32; j++) {
    const float* r = Wb + j * 32;
    float z = 0.f;
#pragma unroll
    for (int k = 0; k < 32; k++) z += tin[k] * r[k];
    float hs, sg;
    sp_sig(tout[j], hs, sg);
    h[j] = hs;
    tout[j] = z * sg;
  }
}

// plain forward layer: hout = softplus(hin @ Wt + b)
__device__ __forceinline__ void fwd_layer(const float* __restrict__ Wb,
                                          const float* __restrict__ bh,
                                          const float* __restrict__ hin, float* __restrict__ hout) {
#pragma unroll
  for (int j = 0; j < 32; j++) {
    const float* r = Wb + j * 32;
    float z = bh[j];
#pragma unroll
    for (int k = 0; k < 32; k++) z += hin[k] * r[k];
    hout[j] = sp1(z);
  }
}

// backward matvec vs ORIGINAL-layout Wh rows: gout[k] = sum_j Wh[k][j] * gin[j]
__device__ __forceinline__ void bwd_mv(const float* __restrict__ Worig,
                                       const float* __restrict__ gin, float* __restrict__ gout) {
#pragma unroll
  for (int k = 0; k < 32; k++) {
    const float* r = Worig + k * 32;
    float s = 0.f;
#pragma unroll
    for (int j = 0; j < 32; j++) s += r[j] * gin[j];
    gout[k] = s;
  }
}

__global__ __launch_bounds__(256, 3) void roles3_lds_kernel(
    const float* __restrict__ in, const float* __restrict__ ws, const float* __restrict__ m_b0,
    const float* __restrict__ m_bh, const float* __restrict__ m_bo, const float* __restrict__ u_W0,
    const float* __restrict__ u_b0, const float* __restrict__ u_Wh, const float* __restrict__ u_bh,
    const float* __restrict__ u_Wo, const float* __restrict__ d_b0, const float* __restrict__ d_bh,
    const float* __restrict__ d_bo, float* __restrict__ sc, int B) {
  __shared__ __align__(16) float W[LDS_FLOATS];
  const int role = blockIdx.x % 3;
  const int t = threadIdx.x;

  // ---- stage role weights + biases into LDS ----
  if (role == 0) {
    cpy4(W, ws + MW0T, 48, t);
    cpy4(W + 192, ws + MWHT, 1024, t);
    cpy4(W + 4288, ws + MWOT, 288, t);
    cpys(W + 5440, m_b0, 32, t);
    cpys(W + 5472, m_bh, 128, t);
    cpys(W + 5600, m_bo, 36, t);
  } else if (role == 1) {
    cpy4(W, ws + UW0T, 48, t);
    cpy4(W + 192, ws + UWHT, 1024, t);
    cpy4(W + 4288, u_Wh, 1024, t);  // original layout for bwd
    cpy4(W + 8384, u_Wo, 8, t);
    cpy4(W + 8416, u_W0, 48, t);  // original layout for final grad
    cpys(W + 8608, u_b0, 32, t);
    cpys(W + 8640, u_bh, 128, t);
  } else {
    cpy4(W, ws + DW0T, 48, t);
    cpy4(W + 192, ws + DWHT, 1024, t);
    cpy4(W + 4288, ws + DWOT, 288, t);
    cpys(W + 5440, d_b0, 32, t);
    cpys(W + 5472, d_bh, 128, t);
    cpys(W + 5600, d_bo, 36, t);
  }
  __syncthreads();

  const int e = (blockIdx.x / 3) * 256 + t;
  if (e >= B) return;
  const float* ip = in + (long)e * 18;
  const long Bl = B;

  float x[6];
#pragma unroll
  for (int i = 0; i < 6; i++) x[i] = ip[i];

  if (role == 0) {
    // ================= m: fwd + JVP =================
    const float* w0 = W;
    const float* wh = W + 192;
    const float* wo = W + 4288;
    const float* b0 = W + 5440;
    const float* bh = W + 5472;
    const float* bo = W + 5600;
    float xd[6];
#pragma unroll
    for (int i = 0; i < 6; i++) xd[i] = ip[6 + i];
    float h[32], tv[32], zn[32];
#pragma unroll
    for (int j = 0; j < 32; j++) {
      const float* r = w0 + j * 6;
      float zh = b0[j], zt = 0.f;
#pragma unroll
      for (int k = 0; k < 6; k++) {
        zh += x[k] * r[k];
        zt += xd[k] * r[k];
      }
      float hs, sg;
      sp_sig(zh, hs, sg);
      h[j] = hs;
      tv[j] = zt * sg;
    }
    m_layer(wh + 0 * 1024, bh + 0, h, tv, zn);
    m_layer(wh + 1 * 1024, bh + 32, h, zn, tv);
    m_layer(wh + 2 * 1024, bh + 64, h, tv, zn);
    m_layer(wh + 3 * 1024, bh + 96, h, zn, tv);
    // symmetrized output, pairwise
    float Ms[21], tc[6] = {0, 0, 0, 0, 0, 0};
    int idx = 0;
#pragma unroll
    for (int i = 0; i < 6; i++)
#pragma unroll
      for (int j = i; j < 6; j++) {
        const float* r = wo + (i * 6 + j) * 32;
        float v = bo[i * 6 + j], w = 0.f;
#pragma unroll
        for (int k = 0; k < 32; k++) {
          v += h[k] * r[k];
          w += tv[k] * r[k];
        }
        if (i != j) {
          const float* r2 = wo + (j * 6 + i) * 32;
          float v2 = bo[j * 6 + i], w2 = 0.f;
#pragma unroll
          for (int k = 0; k < 32; k++) {
            v2 += h[k] * r2[k];
            w2 += tv[k] * r2[k];
          }
          v = 0.5f * (v + v2);
          w = 0.5f * (w + w2);
        }
        Ms[idx] = v;
        tc[i] += w * xd[j];
        if (j != i) tc[j] += w * xd[i];
        idx++;
      }
#pragma unroll
    for (int f = 0; f < 21; f++) sc[f * Bl + e] = Ms[f];
#pragma unroll
    for (int i = 0; i < 6; i++) sc[(21 + i) * Bl + e] = tc[i];
  } else if (role == 1) {
    // ================= u: fwd + checkpointed bwd =================
    const float* w0 = W;
    const float* wh = W + 192;    // transposed (fwd)
    const float* whO = W + 4288;  // original (bwd)
    const float* uwo = W + 8384;
    const float* uw0O = W + 8416;
    const float* b0 = W + 8608;
    const float* bh = W + 8640;
    float hb[32], hd[32], s[32], r2[32];
    // ha -> s
#pragma unroll
    for (int j = 0; j < 32; j++) {
      const float* r = w0 + j * 6;
      float z = b0[j];
#pragma unroll
      for (int k = 0; k < 6; k++) z += x[k] * r[k];
      s[j] = sp1(z);
    }
    fwd_layer(wh + 0 * 1024, bh + 0, s, hb);   // hb (checkpoint)
    fwd_layer(wh + 1 * 1024, bh + 32, hb, s);  // hc (dropped, recomputed later)
    fwd_layer(wh + 2 * 1024, bh + 64, s, hd);  // hd (checkpoint)
    fwd_layer(wh + 3 * 1024, bh + 96, hd, s);  // he
    // g = Wo * sig(he), in place in s
#pragma unroll
    for (int j = 0; j < 32; j++) s[j] = uwo[j] * sig_h(s[j]);
    bwd_mv(whO + 3 * 1024, s, r2);
#pragma unroll
    for (int j = 0; j < 32; j++) s[j] = r2[j] * sig_h(hd[j]);  // hd dead
    bwd_mv(whO + 2 * 1024, s, hd);                             // gn -> hd
    fwd_layer(wh + 1 * 1024, bh + 32, hb, s);                  // recompute hc -> s
#pragma unroll
    for (int j = 0; j < 32; j++) r2[j] = hd[j] * sig_h(s[j]);
    bwd_mv(whO + 1 * 1024, r2, s);
#pragma unroll
    for (int j = 0; j < 32; j++) r2[j] = s[j] * sig_h(hb[j]);  // hb dead
    bwd_mv(whO + 0 * 1024, r2, hb);
    // recompute ha -> s
#pragma unroll
    for (int j = 0; j < 32; j++) {
      const float* r = w0 + j * 6;
      float z = b0[j];
#pragma unroll
      for (int k = 0; k < 6; k++) z += x[k] * r[k];
      s[j] = sp1(z);
    }
#pragma unroll
    for (int j = 0; j < 32; j++) s[j] = hb[j] * sig_h(s[j]);
#pragma unroll
    for (int i = 0; i < 6; i++) {
      const float* r = uw0O + i * 32;  // original layout: row i over j
      float tp = 0.f;
#pragma unroll
      for (int j = 0; j < 32; j++) tp += r[j] * s[j];
      sc[(27 + i) * Bl + e] = tp;
    }
  } else {
    // ================= d: fwd =================
    const float* w0 = W;
    const float* wh = W + 192;
    const float* wo = W + 4288;
    const float* b0 = W + 5440;
    const float* bh = W + 5472;
    const float* bo = W + 5600;
    float xd[6];
#pragma unroll
    for (int i = 0; i < 6; i++) xd[i] = ip[6 + i];
    float h[32], zn[32];
#pragma unroll
    for (int j = 0; j < 32; j++) {
      const float* r = w0 + j * 6;
      float z = b0[j];
#pragma unroll
      for (int k = 0; k < 6; k++) z += x[k] * r[k];
      h[j] = sp1(z);
    }
    fwd_layer(wh + 0 * 1024, bh + 0, h, zn);
    fwd_layer(wh + 1 * 1024, bh + 32, zn, h);
    fwd_layer(wh + 2 * 1024, bh + 64, h, zn);
    fwd_layer(wh + 3 * 1024, bh + 96, zn, h);
    float td[6] = {0, 0, 0, 0, 0, 0};
#pragma unroll
    for (int o = 0; o < 36; o++) {
      const float* r = wo + o * 32;
      float v = bo[o];
#pragma unroll
      for (int k = 0; k < 32; k++) v += h[k] * r[k];
      td[o / 6] += v * xd[o % 6];
    }
#pragma unroll
    for (int i = 0; i < 6; i++) sc[(33 + i) * Bl + e] = td[i];
  }
}

// ---------------- combine + solve ----------------
__global__ __launch_bounds__(256) void combine_kernel(const float* __restrict__ in,
                                                      const float* __restrict__ A,
                                                      const float* __restrict__ sc,
                                                      float* __restrict__ out, int B) {
  int b = blockIdx.x * 256 + threadIdx.x;
  if (b >= B) return;
  const long Bl = B;
  const float* ip = in + (long)b * 18;
  float te[6];
  {
    float tv[6];
#pragma unroll
    for (int i = 0; i < 6; i++) tv[i] = ip[12 + i];
#pragma unroll
    for (int i = 0; i < 6; i++) {
      float s = 0.f;
#pragma unroll
      for (int j = 0; j < 6; j++) s += tv[j] * A[j * 6 + i];
      te[i] = s;
    }
  }
  float Ms[6][6], r[6], y[6];
  {
    int idx = 0;
#pragma unroll
    for (int i = 0; i < 6; i++)
#pragma unroll
      for (int j = i; j < 6; j++) {
        float v = sc[idx * Bl + b];
        Ms[i][j] = v;
        Ms[j][i] = v;
        idx++;
      }
  }
#pragma unroll
  for (int i = 0; i < 6; i++)
    r[i] = te[i] - sc[(21 + i) * Bl + b] - sc[(27 + i) * Bl + b] - sc[(33 + i) * Bl + b];

#pragma unroll
  for (int k = 0; k < 6; k++) {
#pragma unroll
    for (int rr = k + 1; rr < 6; rr++) {
      bool c = fabsf(Ms[rr][k]) > fabsf(Ms[k][k]);
#pragma unroll
      for (int j = 0; j < 6; j++) {
        float a = Ms[k][j], bb = Ms[rr][j];
        Ms[k][j] = c ? bb : a;
        Ms[rr][j] = c ? a : bb;
      }
      float a = r[k], bb = r[rr];
      r[k] = c ? bb : a;
      r[rr] = c ? a : bb;
    }
    float piv = Ms[k][k];
#pragma unroll
    for (int rr = k + 1; rr < 6; rr++) {
      float f = Ms[rr][k] / piv;
#pragma unroll
      for (int j = k; j < 6; j++) Ms[rr][j] -= f * Ms[k][j];
      r[rr] -= f * r[k];
    }
  }
#pragma unroll
  for (int ki = 5; ki >= 0; ki--) {
    float v = r[ki];
#pragma unroll
    for (int j = ki + 1; j < 6; j++) v -= Ms[ki][j] * y[j];
    y[ki] = v / Ms[ki][ki];
  }
  float* op = out + (long)b * 6;
#pragma unroll
  for (int i = 0; i < 6; i++) op[i] = y[i];
}

// ---------------- fallback monolithic kernel (used only if ws too small) ----------------
__global__ __launch_bounds__(64, 1) void lnn_kernel(
    const float* __restrict__ in, const float* __restrict__ A, const float* __restrict__ ws,
    const float* __restrict__ m_b0, const float* __restrict__ m_bh, const float* __restrict__ m_bo,
    const float* __restrict__ u_W0, const float* __restrict__ u_b0, const float* __restrict__ u_Wh,
    const float* __restrict__ u_bh, const float* __restrict__ u_Wo,
    const float* __restrict__ d_b0, const float* __restrict__ d_bh, const float* __restrict__ d_bo,
    float* __restrict__ out, int B) {
  int b = blockIdx.x * 64 + threadIdx.x;
  if (b >= B) return;
  const float* ip = in + (long)b * 18;
  float x[6], xd[6], te[6];
#pragma unroll
  for (int i = 0; i < 6; i++) {
    x[i] = ip[i];
    xd[i] = ip[6 + i];
  }
  {
    float tv[6];
#pragma unroll
    for (int i = 0; i < 6; i++) tv[i] = ip[12 + i];
#pragma unroll
    for (int i = 0; i < 6; i++) {
      float s = 0.f;
#pragma unroll
      for (int j = 0; j < 6; j++) s += tv[j] * A[j * 6 + i];
      te[i] = s;
    }
  }
  float td[6] = {0, 0, 0, 0, 0, 0};
  {
    float h[32], zn[32];
    const float* w0 = ws + DW0T;
#pragma unroll
    for (int j = 0; j < 32; j++) {
      float z = d_b0[j];
#pragma unroll
      for (int k = 0; k < 6; k++) z += x[k] * w0[j * 6 + k];
      h[j] = sp1(z);
    }
    fwd_layer(ws + DWHT + 0 * 1024, d_bh + 0, h, zn);
    fwd_layer(ws + DWHT + 1 * 1024, d_bh + 32, zn, h);
    fwd_layer(ws + DWHT + 2 * 1024, d_bh + 64, h, zn);
    fwd_layer(ws + DWHT + 3 * 1024, d_bh + 96, zn, h);
    const float* wo = ws + DWOT;
#pragma unroll
    for (int o = 0; o < 36; o++) {
      float v = d_bo[o];
#pragma unroll
      for (int k = 0; k < 32; k++) v += h[k] * wo[o * 32 + k];
      td[o / 6] += v * xd[o % 6];
    }
  }
  float tp[6] = {0, 0, 0, 0, 0, 0};
  {
    float hb[32], hd[32], s[32], r2[32];
    const float* w0 = ws + UW0T;
#pragma unroll
    for (int j = 0; j < 32; j++) {
      float z = u_b0[j];
#pragma unroll
      for (int k = 0; k < 6; k++) z += x[k] * w0[j * 6 + k];
      s[j] = sp1(z);
    }
    fwd_layer(ws + UWHT + 0 * 1024, u_bh + 0, s, hb);
    fwd_layer(ws + UWHT + 1 * 1024, u_bh + 32, hb, s);
    fwd_layer(ws + UWHT + 2 * 1024, u_bh + 64, s, hd);
    fwd_layer(ws + UWHT + 3 * 1024, u_bh + 96, hd, s);
#pragma unroll
    for (int j = 0; j < 32; j++) s[j] = u_Wo[j] * sig_h(s[j]);
    bwd_mv(u_Wh + 3 * 1024, s, r2);
#pragma unroll
    for (int j = 0; j < 32; j++) s[j] = r2[j] * sig_h(hd[j]);
    bwd_mv(u_Wh + 2 * 1024, s, hd);
    fwd_layer(ws + UWHT + 1 * 1024, u_bh + 32, hb, s);
#pragma unroll
    for (int j = 0; j < 32; j++) r2[j] = hd[j] * sig_h(s[j]);
    bwd_mv(u_Wh + 1 * 1024, r2, s);
#pragma unroll
    for (int j = 0; j < 32; j++) r2[j] = s[j] * sig_h(hb[j]);
    bwd_mv(u_Wh + 0 * 1024, r2, hb);
#pragma unroll
    for (int j = 0; j < 32; j++) {
      float z = u_b0[j];
#pragma unroll
      for (int k = 0; k < 6; k++) z += x[k] * w0[j * 6 + k];
      s[j] = sp1(z);
    }
#pragma unroll
    for (int j = 0; j < 32; j++) s[j] = hb[j] * sig_h(s[j]);
#pragma unroll
    for (int i = 0; i < 6; i++) {
      float t = 0.f;
#pragma unroll
      for (int j = 0; j < 32; j++) t += u_W0[i * 32 + j] * s[j];
      tp[i] = t;
    }
  }
  float Ms[6][6], tc[6];
  {
    float h[32], t[32], zn[32];
    const float* w0 = ws + MW0T;
#pragma unroll
    for (int j = 0; j < 32; j++) {
      float zh = m_b0[j], zt = 0.f;
#pragma unroll
      for (int k = 0; k < 6; k++) {
        zh += x[k] * w0[j * 6 + k];
        zt += xd[k] * w0[j * 6 + k];
      }
      float hs, sg;
      sp_sig(zh, hs, sg);
      h[j] = hs;
      t[j] = zt * sg;
    }
    m_layer(ws + MWHT + 0 * 1024, m_bh + 0, h, t, zn);
    m_layer(ws + MWHT + 1 * 1024, m_bh + 32, h, zn, t);
    m_layer(ws + MWHT + 2 * 1024, m_bh + 64, h, t, zn);
    m_layer(ws + MWHT + 3 * 1024, m_bh + 96, h, zn, t);
    const float* wo = ws + MWOT;
    float Msv[21];
    int idx = 0;
#pragma unroll
    for (int i = 0; i < 6; i++) tc[i] = 0.f;
#pragma unroll
    for (int i = 0; i < 6; i++)
#pragma unroll
      for (int j = i; j < 6; j++) {
        const float* r = wo + (i * 6 + j) * 32;
        float v = m_bo[i * 6 + j], w = 0.f;
#pragma unroll
        for (int k = 0; k < 32; k++) {
          v += h[k] * r[k];
          w += t[k] * r[k];
        }
        if (i != j) {
          const float* rr = wo + (j * 6 + i) * 32;
          float v2 = m_bo[j * 6 + i], w2 = 0.f;
#pragma unroll
          for (int k = 0; k < 32; k++) {
            v2 += h[k] * rr[k];
            w2 += t[k] * rr[k];
          }
          v = 0.5f * (v + v2);
          w = 0.5f * (w + w2);
        }
        Msv[idx] = v;
        tc[i] += w * xd[j];
        if (j != i) tc[j] += w * xd[i];
        idx++;
      }
    idx = 0;
#pragma unroll
    for (int i = 0; i < 6; i++)
#pragma unroll
      for (int j = i; j < 6; j++) {
        Ms[i][j] = Msv[idx];
        Ms[j][i] = Msv[idx];
        idx++;
      }
  }
  float r[6], y[6];
#pragma unroll
  for (int i = 0; i < 6; i++) r[i] = te[i] - tc[i] - tp[i] - td[i];
#pragma unroll
  for (int k = 0; k < 6; k++) {
#pragma unroll
    for (int rr = k + 1; rr < 6; rr++) {
      bool c = fabsf(Ms[rr][k]) > fabsf(Ms[k][k]);
#pragma unroll
      for (int j = 0; j < 6; j++) {
        float a = Ms[k][j], bb = Ms[rr][j];
        Ms[k][j] = c ? bb : a;
        Ms[rr][j] = c ? a : bb;
      }
      float a = r[k], bb = r[rr];
      r[k] = c ? bb : a;
      r[rr] = c ? a : bb;
    }
    float piv = Ms[k][k];
#pragma unroll
    for (int rr = k + 1; rr < 6; rr++) {
      float f = Ms[rr][k] / piv;
#pragma unroll
      for (int j = k; j < 6; j++) Ms[rr][j] -= f * Ms[k][j];
      r[rr] -= f * r[k];
    }
  }
#pragma unroll
  for (int ki = 5; ki >= 0; ki--) {
    float v = r[ki];
#pragma unroll
    for (int j = ki + 1; j < 6; j++) v -= Ms[ki][j] * y[j];
    y[ki] = v / Ms[ki][ki];
  }
  float* op = out + (long)b * 6;
#pragma unroll
  for (int i = 0; i < 6; i++) op[i] = y[i];
}

extern "C" void kernel_launch(void* const* d_in, const int* in_sizes, int n_in, void* d_out,
                              int out_size, void* d_ws, size_t ws_size, hipStream_t stream) {
  const float* inputs = (const float*)d_in[0];
  const float* A = (const float*)d_in[1];
  const float* m_W0 = (const float*)d_in[2];
  const float* m_b0 = (const float*)d_in[3];
  const float* m_Wh = (const float*)d_in[4];
  const float* m_bh = (const float*)d_in[5];
  const float* m_Wo = (const float*)d_in[6];
  const float* m_bo = (const float*)d_in[7];
  const float* u_W0 = (const float*)d_in[8];
  const float* u_b0 = (const float*)d_in[9];
  const float* u_Wh = (const float*)d_in[10];
  const float* u_bh = (const float*)d_in[11];
  const float* u_Wo = (const float*)d_in[12];
  const float* d_W0 = (const float*)d_in[14];
  const float* d_b0 = (const float*)d_in[15];
  const float* d_Wh = (const float*)d_in[16];
  const float* d_bh = (const float*)d_in[17];
  const float* d_Wo = (const float*)d_in[18];
  const float* d_bo = (const float*)d_in[19];

  float* ws = (float*)d_ws;
  float* out = (float*)d_out;
  int B = in_sizes[0] / 18;

  prep_kernel<<<16, 256, 0, stream>>>(m_W0, m_Wh, m_Wo, u_W0, u_Wh, u_Wo, d_W0, d_Wh, d_Wo, ws);

  size_t need = (size_t)(SC_BASE + (size_t)B * 39) * 4;
  if (ws_size >= need) {
    float* sc = ws + SC_BASE;
    int nb = (B + 255) / 256;
    roles3_lds_kernel<<<3 * nb, 256, 0, stream>>>(inputs, ws, m_b0, m_bh, m_bo, u_W0, u_b0, u_Wh,
                                                  u_bh, u_Wo, d_b0, d_bh, d_bo, sc, B);
    combine_kernel<<<(B + 255) / 256, 256, 0, stream>>>(inputs, A, sc, out, B);
  } else {
    lnn_kernel<<<(B + 63) / 64, 64, 0, stream>>>(inputs, A, ws, m_b0, m_bh, m_bo, u_W0, u_b0, u_Wh,
                                                 u_bh, u_Wo, d_b0, d_bh, d_bo, out, B);
  }
}

// Round 2
// 252.283 us; speedup vs baseline: 2.1739x; 2.1739x over previous
//
#include <hip/hip_runtime.h>

// LnnDynamics, role-per-block + LDS-weight version (v3):
//   role 0 (m): M-MLP fwd + JVP along qd -> Ms[21] (symmetrized), tc[6]
//   role 1 (u): U-MLP fwd + checkpointed reverse-mode -> tau_pot[6]
//   role 2 (d): D-MLP fwd -> tau_d[6]
//   combine:   r = tau@A - tc - tp - td ; solve Msym y = r
// v2 -> v3: ONLY change is __launch_bounds__(256,3) -> (256,2).
// v2's (256,3) capped VGPRs at ~170; the LDS-weight path needs ~190-200
// (weight values arrive in VGPRs via ds_read_b128, several rows in
// flight) -> allocator spilled the activation arrays to scratch
// (WRITE_SIZE 833 MB, VGPR_Count 84, 548 us). (256,2) gives a 256-VGPR
// cap: no spill, 2 waves/SIMD, 2 blocks/CU (70 KB LDS of 160).
// Scratch sc is SoA: sc[field*B + b], fields 0-20 Ms, 21-26 tc, 27-32 tp, 33-38 td.

#define NQ 6
#define HID 32
#define NHID 4  // NL-1

// workspace float offsets (transposed weights, built by prep_kernel)
#define MW0T 0
#define UW0T 192
#define DW0T 384
#define MWHT 576
#define UWHT (576 + 4096)
#define DWHT (576 + 8192)
#define MWOT (576 + 12288)
#define DWOT (MWOT + 1152)
#define UWOT (DWOT + 1152)
#define SC_BASE 16384  // per-element scratch starts here (floats)

// LDS layout (floats):
//  role m/d: [0:192) W0t | [192:4288) Wht | [4288:5440) Wot
//            [5440:5472) b0 | [5472:5600) bh | [5600:5636) bo
//  role u:   [0:192) W0t | [192:4288) Wht | [4288:8384) Wh-original
//            [8384:8416) Wo | [8416:8608) W0-original
//            [8608:8640) b0 | [8640:8768) bh
#define LDS_FLOATS 8768

__global__ void prep_kernel(const float* __restrict__ mW0, const float* __restrict__ mWh,
                            const float* __restrict__ mWo, const float* __restrict__ uW0,
                            const float* __restrict__ uWh, const float* __restrict__ uWo,
                            const float* __restrict__ dW0, const float* __restrict__ dWh,
                            const float* __restrict__ dWo, float* __restrict__ ws) {
  int t = blockIdx.x * blockDim.x + threadIdx.x;
  if (t < 192) {  // W0t[j*6+k] = W0[k*32+j]
    int j = t / 6, k = t % 6;
    ws[MW0T + t] = mW0[k * HID + j];
    ws[UW0T + t] = uW0[k * HID + j];
    ws[DW0T + t] = dW0[k * HID + j];
  }
  if (t < 4096) {  // Wht[(l*32+j)*32+k] = Wh[(l*32+k)*32+j]
    int l = t >> 10, j = (t >> 5) & 31, k = t & 31;
    int src = l * 1024 + k * 32 + j;
    ws[MWHT + t] = mWh[src];
    ws[UWHT + t] = uWh[src];
    ws[DWHT + t] = dWh[src];
  }
  if (t < 1152) {  // Wot[o*32+k] = Wo[k*36+o]
    int o = t / 32, k = t % 32;
    ws[MWOT + t] = mWo[k * 36 + o];
    ws[DWOT + t] = dWo[k * 36 + o];
  }
  if (t < 32) ws[UWOT + t] = uWo[t];
}

__device__ __forceinline__ float sp1(float z) {
  return fmaxf(z, 0.f) + __logf(1.f + __expf(-fabsf(z)));
}
__device__ __forceinline__ void sp_sig(float z, float& hs, float& sg) {
  float e = __expf(-fabsf(z));
  float d = __builtin_amdgcn_rcpf(1.f + e);
  hs = fmaxf(z, 0.f) + __logf(1.f + e);
  sg = (z >= 0.f ? 1.f : e) * d;
}
// h = softplus(z) >= 0  =>  sigmoid(z) = 1 - exp(-h)
__device__ __forceinline__ float sig_h(float h) { return 1.f - __expf(-h); }

// block-cooperative copies into LDS (256 threads)
__device__ __forceinline__ void cpy4(float* __restrict__ dst, const float* __restrict__ src,
                                     int n4, int t) {
  const float4* s = (const float4*)src;
  float4* d = (float4*)dst;
  for (int i = t; i < n4; i += 256) d[i] = s[i];
}
__device__ __forceinline__ void cpys(float* __restrict__ dst, const float* __restrict__ src, int n,
                                     int t) {
  for (int i = t; i < n; i += 256) dst[i] = src[i];
}

// m-role layer, two-pass (keeps only h + tin + tout live):
//   pass A: tout_j = zh_j = h . Wt_j + b_j
//   pass B: zt_j = tin . Wt_j ; h_j = softplus(zh_j) ; tout_j = zt_j * sigmoid(zh_j)
__device__ __forceinline__ void m_layer(const float* __restrict__ Wb, const float* __restrict__ bh,
                                        float* __restrict__ h, const float* __restrict__ tin,
                                        float* __restrict__ tout) {
#pragma unroll
  for (int j = 0; j < 32; j++) {
    const float* r = Wb + j * 32;
    float z = bh[j];
#pragma unroll
    for (int k = 0; k < 32; k++) z += h[k] * r[k];
    tout[j] = z;
  }
#pragma unroll
  for (int j = 0; j < 32; j++) {
    const float* r = Wb + j * 32;
    float z = 0.f;
#pragma unroll
    for (int k = 0; k < 32; k++) z += tin[k] * r[k];
    float hs, sg;
    sp_sig(tout[j], hs, sg);
    h[j] = hs;
    tout[j] = z * sg;
  }
}

// plain forward layer: hout = softplus(hin @ Wt + b)
__device__ __forceinline__ void fwd_layer(const float* __restrict__ Wb,
                                          const float* __restrict__ bh,
                                          const float* __restrict__ hin, float* __restrict__ hout) {
#pragma unroll
  for (int j = 0; j < 32; j++) {
    const float* r = Wb + j * 32;
    float z = bh[j];
#pragma unroll
    for (int k = 0; k < 32; k++) z += hin[k] * r[k];
    hout[j] = sp1(z);
  }
}

// backward matvec vs ORIGINAL-layout Wh rows: gout[k] = sum_j Wh[k][j] * gin[j]
__device__ __forceinline__ void bwd_mv(const float* __restrict__ Worig,
                                       const float* __restrict__ gin, float* __restrict__ gout) {
#pragma unroll
  for (int k = 0; k < 32; k++) {
    const float* r = Worig + k * 32;
    float s = 0.f;
#pragma unroll
    for (int j = 0; j < 32; j++) s += r[j] * gin[j];
    gout[k] = s;
  }
}

__global__ __launch_bounds__(256, 2) void roles3_lds_kernel(
    const float* __restrict__ in, const float* __restrict__ ws, const float* __restrict__ m_b0,
    const float* __restrict__ m_bh, const float* __restrict__ m_bo, const float* __restrict__ u_W0,
    const float* __restrict__ u_b0, const float* __restrict__ u_Wh, const float* __restrict__ u_bh,
    const float* __restrict__ u_Wo, const float* __restrict__ d_b0, const float* __restrict__ d_bh,
    const float* __restrict__ d_bo, float* __restrict__ sc, int B) {
  __shared__ __align__(16) float W[LDS_FLOATS];
  const int role = blockIdx.x % 3;
  const int t = threadIdx.x;

  // ---- stage role weights + biases into LDS ----
  if (role == 0) {
    cpy4(W, ws + MW0T, 48, t);
    cpy4(W + 192, ws + MWHT, 1024, t);
    cpy4(W + 4288, ws + MWOT, 288, t);
    cpys(W + 5440, m_b0, 32, t);
    cpys(W + 5472, m_bh, 128, t);
    cpys(W + 5600, m_bo, 36, t);
  } else if (role == 1) {
    cpy4(W, ws + UW0T, 48, t);
    cpy4(W + 192, ws + UWHT, 1024, t);
    cpy4(W + 4288, u_Wh, 1024, t);  // original layout for bwd
    cpy4(W + 8384, u_Wo, 8, t);
    cpy4(W + 8416, u_W0, 48, t);  // original layout for final grad
    cpys(W + 8608, u_b0, 32, t);
    cpys(W + 8640, u_bh, 128, t);
  } else {
    cpy4(W, ws + DW0T, 48, t);
    cpy4(W + 192, ws + DWHT, 1024, t);
    cpy4(W + 4288, ws + DWOT, 288, t);
    cpys(W + 5440, d_b0, 32, t);
    cpys(W + 5472, d_bh, 128, t);
    cpys(W + 5600, d_bo, 36, t);
  }
  __syncthreads();

  const int e = (blockIdx.x / 3) * 256 + t;
  if (e >= B) return;
  const float* ip = in + (long)e * 18;
  const long Bl = B;

  float x[6];
#pragma unroll
  for (int i = 0; i < 6; i++) x[i] = ip[i];

  if (role == 0) {
    // ================= m: fwd + JVP =================
    const float* w0 = W;
    const float* wh = W + 192;
    const float* wo = W + 4288;
    const float* b0 = W + 5440;
    const float* bh = W + 5472;
    const float* bo = W + 5600;
    float xd[6];
#pragma unroll
    for (int i = 0; i < 6; i++) xd[i] = ip[6 + i];
    float h[32], tv[32], zn[32];
#pragma unroll
    for (int j = 0; j < 32; j++) {
      const float* r = w0 + j * 6;
      float zh = b0[j], zt = 0.f;
#pragma unroll
      for (int k = 0; k < 6; k++) {
        zh += x[k] * r[k];
        zt += xd[k] * r[k];
      }
      float hs, sg;
      sp_sig(zh, hs, sg);
      h[j] = hs;
      tv[j] = zt * sg;
    }
    m_layer(wh + 0 * 1024, bh + 0, h, tv, zn);
    m_layer(wh + 1 * 1024, bh + 32, h, zn, tv);
    m_layer(wh + 2 * 1024, bh + 64, h, tv, zn);
    m_layer(wh + 3 * 1024, bh + 96, h, zn, tv);
    // symmetrized output, pairwise
    float Ms[21], tc[6] = {0, 0, 0, 0, 0, 0};
    int idx = 0;
#pragma unroll
    for (int i = 0; i < 6; i++)
#pragma unroll
      for (int j = i; j < 6; j++) {
        const float* r = wo + (i * 6 + j) * 32;
        float v = bo[i * 6 + j], w = 0.f;
#pragma unroll
        for (int k = 0; k < 32; k++) {
          v += h[k] * r[k];
          w += tv[k] * r[k];
        }
        if (i != j) {
          const float* r2 = wo + (j * 6 + i) * 32;
          float v2 = bo[j * 6 + i], w2 = 0.f;
#pragma unroll
          for (int k = 0; k < 32; k++) {
            v2 += h[k] * r2[k];
            w2 += tv[k] * r2[k];
          }
          v = 0.5f * (v + v2);
          w = 0.5f * (w + w2);
        }
        Ms[idx] = v;
        tc[i] += w * xd[j];
        if (j != i) tc[j] += w * xd[i];
        idx++;
      }
#pragma unroll
    for (int f = 0; f < 21; f++) sc[f * Bl + e] = Ms[f];
#pragma unroll
    for (int i = 0; i < 6; i++) sc[(21 + i) * Bl + e] = tc[i];
  } else if (role == 1) {
    // ================= u: fwd + checkpointed bwd =================
    const float* w0 = W;
    const float* wh = W + 192;    // transposed (fwd)
    const float* whO = W + 4288;  // original (bwd)
    const float* uwo = W + 8384;
    const float* uw0O = W + 8416;
    const float* b0 = W + 8608;
    const float* bh = W + 8640;
    float hb[32], hd[32], s[32], r2[32];
    // ha -> s
#pragma unroll
    for (int j = 0; j < 32; j++) {
      const float* r = w0 + j * 6;
      float z = b0[j];
#pragma unroll
      for (int k = 0; k < 6; k++) z += x[k] * r[k];
      s[j] = sp1(z);
    }
    fwd_layer(wh + 0 * 1024, bh + 0, s, hb);   // hb (checkpoint)
    fwd_layer(wh + 1 * 1024, bh + 32, hb, s);  // hc (dropped, recomputed later)
    fwd_layer(wh + 2 * 1024, bh + 64, s, hd);  // hd (checkpoint)
    fwd_layer(wh + 3 * 1024, bh + 96, hd, s);  // he
    // g = Wo * sig(he), in place in s
#pragma unroll
    for (int j = 0; j < 32; j++) s[j] = uwo[j] * sig_h(s[j]);
    bwd_mv(whO + 3 * 1024, s, r2);
#pragma unroll
    for (int j = 0; j < 32; j++) s[j] = r2[j] * sig_h(hd[j]);  // hd dead
    bwd_mv(whO + 2 * 1024, s, hd);                             // gn -> hd
    fwd_layer(wh + 1 * 1024, bh + 32, hb, s);                  // recompute hc -> s
#pragma unroll
    for (int j = 0; j < 32; j++) r2[j] = hd[j] * sig_h(s[j]);
    bwd_mv(whO + 1 * 1024, r2, s);
#pragma unroll
    for (int j = 0; j < 32; j++) r2[j] = s[j] * sig_h(hb[j]);  // hb dead
    bwd_mv(whO + 0 * 1024, r2, hb);
    // recompute ha -> s
#pragma unroll
    for (int j = 0; j < 32; j++) {
      const float* r = w0 + j * 6;
      float z = b0[j];
#pragma unroll
      for (int k = 0; k < 6; k++) z += x[k] * r[k];
      s[j] = sp1(z);
    }
#pragma unroll
    for (int j = 0; j < 32; j++) s[j] = hb[j] * sig_h(s[j]);
#pragma unroll
    for (int i = 0; i < 6; i++) {
      const float* r = uw0O + i * 32;  // original layout: row i over j
      float tp = 0.f;
#pragma unroll
      for (int j = 0; j < 32; j++) tp += r[j] * s[j];
      sc[(27 + i) * Bl + e] = tp;
    }
  } else {
    // ================= d: fwd =================
    const float* w0 = W;
    const float* wh = W + 192;
    const float* wo = W + 4288;
    const float* b0 = W + 5440;
    const float* bh = W + 5472;
    const float* bo = W + 5600;
    float xd[6];
#pragma unroll
    for (int i = 0; i < 6; i++) xd[i] = ip[6 + i];
    float h[32], zn[32];
#pragma unroll
    for (int j = 0; j < 32; j++) {
      const float* r = w0 + j * 6;
      float z = b0[j];
#pragma unroll
      for (int k = 0; k < 6; k++) z += x[k] * r[k];
      h[j] = sp1(z);
    }
    fwd_layer(wh + 0 * 1024, bh + 0, h, zn);
    fwd_layer(wh + 1 * 1024, bh + 32, zn, h);
    fwd_layer(wh + 2 * 1024, bh + 64, h, zn);
    fwd_layer(wh + 3 * 1024, bh + 96, zn, h);
    float td[6] = {0, 0, 0, 0, 0, 0};
#pragma unroll
    for (int o = 0; o < 36; o++) {
      const float* r = wo + o * 32;
      float v = bo[o];
#pragma unroll
      for (int k = 0; k < 32; k++) v += h[k] * r[k];
      td[o / 6] += v * xd[o % 6];
    }
#pragma unroll
    for (int i = 0; i < 6; i++) sc[(33 + i) * Bl + e] = td[i];
  }
}

// ---------------- combine + solve ----------------
__global__ __launch_bounds__(256) void combine_kernel(const float* __restrict__ in,
                                                      const float* __restrict__ A,
                                                      const float* __restrict__ sc,
                                                      float* __restrict__ out, int B) {
  int b = blockIdx.x * 256 + threadIdx.x;
  if (b >= B) return;
  const long Bl = B;
  const float* ip = in + (long)b * 18;
  float te[6];
  {
    float tv[6];
#pragma unroll
    for (int i = 0; i < 6; i++) tv[i] = ip[12 + i];
#pragma unroll
    for (int i = 0; i < 6; i++) {
      float s = 0.f;
#pragma unroll
      for (int j = 0; j < 6; j++) s += tv[j] * A[j * 6 + i];
      te[i] = s;
    }
  }
  float Ms[6][6], r[6], y[6];
  {
    int idx = 0;
#pragma unroll
    for (int i = 0; i < 6; i++)
#pragma unroll
      for (int j = i; j < 6; j++) {
        float v = sc[idx * Bl + b];
        Ms[i][j] = v;
        Ms[j][i] = v;
        idx++;
      }
  }
#pragma unroll
  for (int i = 0; i < 6; i++)
    r[i] = te[i] - sc[(21 + i) * Bl + b] - sc[(27 + i) * Bl + b] - sc[(33 + i) * Bl + b];

#pragma unroll
  for (int k = 0; k < 6; k++) {
#pragma unroll
    for (int rr = k + 1; rr < 6; rr++) {
      bool c = fabsf(Ms[rr][k]) > fabsf(Ms[k][k]);
#pragma unroll
      for (int j = 0; j < 6; j++) {
        float a = Ms[k][j], bb = Ms[rr][j];
        Ms[k][j] = c ? bb : a;
        Ms[rr][j] = c ? a : bb;
      }
      float a = r[k], bb = r[rr];
      r[k] = c ? bb : a;
      r[rr] = c ? a : bb;
    }
    float piv = Ms[k][k];
#pragma unroll
    for (int rr = k + 1; rr < 6; rr++) {
      float f = Ms[rr][k] / piv;
#pragma unroll
      for (int j = k; j < 6; j++) Ms[rr][j] -= f * Ms[k][j];
      r[rr] -= f * r[k];
    }
  }
#pragma unroll
  for (int ki = 5; ki >= 0; ki--) {
    float v = r[ki];
#pragma unroll
    for (int j = ki + 1; j < 6; j++) v -= Ms[ki][j] * y[j];
    y[ki] = v / Ms[ki][ki];
  }
  float* op = out + (long)b * 6;
#pragma unroll
  for (int i = 0; i < 6; i++) op[i] = y[i];
}

// ---------------- fallback monolithic kernel (used only if ws too small) ----------------
__global__ __launch_bounds__(64, 1) void lnn_kernel(
    const float* __restrict__ in, const float* __restrict__ A, const float* __restrict__ ws,
    const float* __restrict__ m_b0, const float* __restrict__ m_bh, const float* __restrict__ m_bo,
    const float* __restrict__ u_W0, const float* __restrict__ u_b0, const float* __restrict__ u_Wh,
    const float* __restrict__ u_bh, const float* __restrict__ u_Wo,
    const float* __restrict__ d_b0, const float* __restrict__ d_bh, const float* __restrict__ d_bo,
    float* __restrict__ out, int B) {
  int b = blockIdx.x * 64 + threadIdx.x;
  if (b >= B) return;
  const float* ip = in + (long)b * 18;
  float x[6], xd[6], te[6];
#pragma unroll
  for (int i = 0; i < 6; i++) {
    x[i] = ip[i];
    xd[i] = ip[6 + i];
  }
  {
    float tv[6];
#pragma unroll
    for (int i = 0; i < 6; i++) tv[i] = ip[12 + i];
#pragma unroll
    for (int i = 0; i < 6; i++) {
      float s = 0.f;
#pragma unroll
      for (int j = 0; j < 6; j++) s += tv[j] * A[j * 6 + i];
      te[i] = s;
    }
  }
  float td[6] = {0, 0, 0, 0, 0, 0};
  {
    float h[32], zn[32];
    const float* w0 = ws + DW0T;
#pragma unroll
    for (int j = 0; j < 32; j++) {
      float z = d_b0[j];
#pragma unroll
      for (int k = 0; k < 6; k++) z += x[k] * w0[j * 6 + k];
      h[j] = sp1(z);
    }
    fwd_layer(ws + DWHT + 0 * 1024, d_bh + 0, h, zn);
    fwd_layer(ws + DWHT + 1 * 1024, d_bh + 32, zn, h);
    fwd_layer(ws + DWHT + 2 * 1024, d_bh + 64, h, zn);
    fwd_layer(ws + DWHT + 3 * 1024, d_bh + 96, zn, h);
    const float* wo = ws + DWOT;
#pragma unroll
    for (int o = 0; o < 36; o++) {
      float v = d_bo[o];
#pragma unroll
      for (int k = 0; k < 32; k++) v += h[k] * wo[o * 32 + k];
      td[o / 6] += v * xd[o % 6];
    }
  }
  float tp[6] = {0, 0, 0, 0, 0, 0};
  {
    float hb[32], hd[32], s[32], r2[32];
    const float* w0 = ws + UW0T;
#pragma unroll
    for (int j = 0; j < 32; j++) {
      float z = u_b0[j];
#pragma unroll
      for (int k = 0; k < 6; k++) z += x[k] * w0[j * 6 + k];
      s[j] = sp1(z);
    }
    fwd_layer(ws + UWHT + 0 * 1024, u_bh + 0, s, hb);
    fwd_layer(ws + UWHT + 1 * 1024, u_bh + 32, hb, s);
    fwd_layer(ws + UWHT + 2 * 1024, u_bh + 64, s, hd);
    fwd_layer(ws + UWHT + 3 * 1024, u_bh + 96, hd, s);
#pragma unroll
    for (int j = 0; j < 32; j++) s[j] = u_Wo[j] * sig_h(s[j]);
    bwd_mv(u_Wh + 3 * 1024, s, r2);
#pragma unroll
    for (int j = 0; j < 32; j++) s[j] = r2[j] * sig_h(hd[j]);
    bwd_mv(u_Wh + 2 * 1024, s, hd);
    fwd_layer(ws + UWHT + 1 * 1024, u_bh + 32, hb, s);
#pragma unroll
    for (int j = 0; j < 32; j++) r2[j] = hd[j] * sig_h(s[j]);
    bwd_mv(u_Wh + 1 * 1024, r2, s);
#pragma unroll
    for (int j = 0; j < 32; j++) r2[j] = s[j] * sig_h(hb[j]);
    bwd_mv(u_Wh + 0 * 1024, r2, hb);
#pragma unroll
    for (int j = 0; j < 32; j++) {
      float z = u_b0[j];
#pragma unroll
      for (int k = 0; k < 6; k++) z += x[k] * w0[j * 6 + k];
      s[j] = sp1(z);
    }
#pragma unroll
    for (int j = 0; j < 32; j++) s[j] = hb[j] * sig_h(s[j]);
#pragma unroll
    for (int i = 0; i < 6; i++) {
      float t = 0.f;
#pragma unroll
      for (int j = 0; j < 32; j++) t += u_W0[i * 32 + j] * s[j];
      tp[i] = t;
    }
  }
  float Ms[6][6], tc[6];
  {
    float h[32], t[32], zn[32];
    const float* w0 = ws + MW0T;
#pragma unroll
    for (int j = 0; j < 32; j++) {
      float zh = m_b0[j], zt = 0.f;
#pragma unroll
      for (int k = 0; k < 6; k++) {
        zh += x[k] * w0[j * 6 + k];
        zt += xd[k] * w0[j * 6 + k];
      }
      float hs, sg;
      sp_sig(zh, hs, sg);
      h[j] = hs;
      t[j] = zt * sg;
    }
    m_layer(ws + MWHT + 0 * 1024, m_bh + 0, h, t, zn);
    m_layer(ws + MWHT + 1 * 1024, m_bh + 32, h, zn, t);
    m_layer(ws + MWHT + 2 * 1024, m_bh + 64, h, t, zn);
    m_layer(ws + MWHT + 3 * 1024, m_bh + 96, h, zn, t);
    const float* wo = ws + MWOT;
    float Msv[21];
    int idx = 0;
#pragma unroll
    for (int i = 0; i < 6; i++) tc[i] = 0.f;
#pragma unroll
    for (int i = 0; i < 6; i++)
#pragma unroll
      for (int j = i; j < 6; j++) {
        const float* r = wo + (i * 6 + j) * 32;
        float v = m_bo[i * 6 + j], w = 0.f;
#pragma unroll
        for (int k = 0; k < 32; k++) {
          v += h[k] * r[k];
          w += t[k] * r[k];
        }
        if (i != j) {
          const float* rr = wo + (j * 6 + i) * 32;
          float v2 = m_bo[j * 6 + i], w2 = 0.f;
#pragma unroll
          for (int k = 0; k < 32; k++) {
            v2 += h[k] * rr[k];
            w2 += t[k] * rr[k];
          }
          v = 0.5f * (v + v2);
          w = 0.5f * (w + w2);
        }
        Msv[idx] = v;
        tc[i] += w * xd[j];
        if (j != i) tc[j] += w * xd[i];
        idx++;
      }
    idx = 0;
#pragma unroll
    for (int i = 0; i < 6; i++)
#pragma unroll
      for (int j = i; j < 6; j++) {
        Ms[i][j] = Msv[idx];
        Ms[j][i] = Msv[idx];
        idx++;
      }
  }
  float r[6], y[6];
#pragma unroll
  for (int i = 0; i < 6; i++) r[i] = te[i] - tc[i] - tp[i] - td[i];
#pragma unroll
  for (int k = 0; k < 6; k++) {
#pragma unroll
    for (int rr = k + 1; rr < 6; rr++) {
      bool c = fabsf(Ms[rr][k]) > fabsf(Ms[k][k]);
#pragma unroll
      for (int j = 0; j < 6; j++) {
        float a = Ms[k][j], bb = Ms[rr][j];
        Ms[k][j] = c ? bb : a;
        Ms[rr][j] = c ? a : bb;
      }
      float a = r[k], bb = r[rr];
      r[k] = c ? bb : a;
      r[rr] = c ? a : bb;
    }
    float piv = Ms[k][k];
#pragma unroll
    for (int rr = k + 1; rr < 6; rr++) {
      float f = Ms[rr][k] / piv;
#pragma unroll
      for (int j = k; j < 6; j++) Ms[rr][j] -= f * Ms[k][j];
      r[rr] -= f * r[k];
    }
  }
#pragma unroll
  for (int ki = 5; ki >= 0; ki--) {
    float v = r[ki];
#pragma unroll
    for (int j = ki + 1; j < 6; j++) v -= Ms[ki][j] * y[j];
    y[ki] = v / Ms[ki][ki];
  }
  float* op = out + (long)b * 6;
#pragma unroll
  for (int i = 0; i < 6; i++) op[i] = y[i];
}

extern "C" void kernel_launch(void* const* d_in, const int* in_sizes, int n_in, void* d_out,
                              int out_size, void* d_ws, size_t ws_size, hipStream_t stream) {
  const float* inputs = (const float*)d_in[0];
  const float* A = (const float*)d_in[1];
  const float* m_W0 = (const float*)d_in[2];
  const float* m_b0 = (const float*)d_in[3];
  const float* m_Wh = (const float*)d_in[4];
  const float* m_bh = (const float*)d_in[5];
  const float* m_Wo = (const float*)d_in[6];
  const float* m_bo = (const float*)d_in[7];
  const float* u_W0 = (const float*)d_in[8];
  const float* u_b0 = (const float*)d_in[9];
  const float* u_Wh = (const float*)d_in[10];
  const float* u_bh = (const float*)d_in[11];
  const float* u_Wo = (const float*)d_in[12];
  const float* d_W0 = (const float*)d_in[14];
  const float* d_b0 = (const float*)d_in[15];
  const float* d_Wh = (const float*)d_in[16];
  const float* d_bh = (const float*)d_in[17];
  const float* d_Wo = (const float*)d_in[18];
  const float* d_bo = (const float*)d_in[19];

  float* ws = (float*)d_ws;
  float* out = (float*)d_out;
  int B = in_sizes[0] / 18;

  prep_kernel<<<16, 256, 0, stream>>>(m_W0, m_Wh, m_Wo, u_W0, u_Wh, u_Wo, d_W0, d_Wh, d_Wo, ws);

  size_t need = (size_t)(SC_BASE + (size_t)B * 39) * 4;
  if (ws_size >= need) {
    float* sc = ws + SC_BASE;
    int nb = (B + 255) / 256;
    roles3_lds_kernel<<<3 * nb, 256, 0, stream>>>(inputs, ws, m_b0, m_bh, m_bo, u_W0, u_b0, u_Wh,
                                                  u_bh, u_Wo, d_b0, d_bh, d_bo, sc, B);
    combine_kernel<<<(B + 255) / 256, 256, 0, stream>>>(inputs, A, sc, out, B);
  } else {
    lnn_kernel<<<(B + 63) / 64, 64, 0, stream>>>(inputs, A, ws, m_b0, m_bh, m_bo, u_W0, u_b0, u_Wh,
                                                 u_bh, u_Wo, d_b0, d_bh, d_bo, out, B);
  }
}